// Round 3
// baseline (1398.395 us; speedup 1.0000x reference)
//
#include <hip/hip_runtime.h>
#include <math.h>

// Capsule dynamic routing, fused-recompute formulation. fp32.
// B=512, R=1152, C=10, O=16, I=8.
//   iter0: c_ij = 1/10 uniform  -> s0 = 0.1 * sum_r u_hat
//   iter2: b2 = u.(v0+v1)       -> only a running vsum is kept
// R2 counters: VALUBusy 10%, HBM 1.4%, Occ 12% -> pure latency stall.
// R3 changes: (1) x transposed once to x_t[r][b][i] (kills 36KB-stride
// 16-line gather on the critical path); (2) unroll-2 + explicit next-r
// x prefetch (unroll 1 had forbidden cross-iteration pipelining);
// (3) RT=192 grid + __launch_bounds__(256,3) -> 12 waves/CU; reduce
// kernel parallelized 4x with LDS combine.

#define R_TOT 1152
#define C_N 10
#define O_N 16
#define I_N 8
#define B_TOT 512
#define SEG (B_TOT * C_N * O_N)                 // 81920 floats per partial slice
#define XT_ELEMS ((size_t)B_TOT * R_TOT * I_N)  // 4,718,592 floats (18.9 MB)

// x[b][r][i] -> x_t[r][b][i]; coalesced reads, scattered 32B writes.
__global__ __launch_bounds__(256) void transpose_x(
    const float* __restrict__ x, float* __restrict__ xt)
{
  const int t = blockIdx.x * 256 + threadIdx.x;   // t = b*R_TOT + r
  const int b = t / R_TOT;
  const int r = t - b * R_TOT;
  const float4* src = reinterpret_cast<const float4*>(x) + (size_t)t * 2;
  float4* dst = reinterpret_cast<float4*>(xt) + ((size_t)r * B_TOT + b) * 2;
  dst[0] = src[0];
  dst[1] = src[1];
}

// lane map: ol = lane&3 owns o in [ol*4,ol*4+4); bl = lane>>2 (16 b / wave)
// grid: (RT, 8) -> blockIdx.x = rtile, blockIdx.y = btile (64 b / block)
template<bool UNIFORM, bool XT>
__global__ __launch_bounds__(256, 3) void acc_kernel(
    const float* __restrict__ x, const float* __restrict__ W,
    const float* __restrict__ vsum, float* __restrict__ part, int RCH)
{
  const int tid   = threadIdx.x;
  const int wave  = tid >> 6;
  const int lane  = tid & 63;
  const int ol    = lane & 3;
  const int bl    = lane >> 2;
  const int obase = ol * 4;
  const int rtile = blockIdx.x;
  const int btile = blockIdx.y;
  const int b     = btile * 64 + wave * 16 + bl;
  const int r0    = rtile * RCH;

  float vf[C_N][4];
  if constexpr (!UNIFORM) {
    #pragma unroll
    for (int c = 0; c < C_N; ++c) {
      const float4 t = *reinterpret_cast<const float4*>(&vsum[(b * C_N + c) * O_N + obase]);
      vf[c][0] = t.x; vf[c][1] = t.y; vf[c][2] = t.z; vf[c][3] = t.w;
    }
  }

  float sacc[C_N][4];
  #pragma unroll
  for (int c = 0; c < C_N; ++c)
    #pragma unroll
    for (int j = 0; j < 4; ++j) sacc[c][j] = 0.0f;

  auto xaddr = [&](int r) -> const float4* {
    if constexpr (XT)
      return reinterpret_cast<const float4*>(x) + ((size_t)r * B_TOT + b) * 2;
    else
      return reinterpret_cast<const float4*>(x) + ((size_t)b * R_TOT + r) * 2;
  };

  // prefetch x for r0
  float4 xa = xaddr(r0)[0];
  float4 xb = xaddr(r0)[1];

  #pragma unroll 2
  for (int rr = 0; rr < RCH; ++rr) {
    const int r = r0 + rr;
    // issue next-iteration x load early (clamped; redundant on last iter)
    const int rn = (rr + 1 < RCH) ? (r + 1) : r;
    const float4 nxa = xaddr(rn)[0];
    const float4 nxb = xaddr(rn)[1];

    const float* Wr = &W[(size_t)r * (C_N * O_N * I_N)];
    float u[C_N][4];
    #pragma unroll
    for (int c = 0; c < C_N; ++c) {
      const float4* wp = reinterpret_cast<const float4*>(&Wr[(c * O_N + obase) * I_N]);
      #pragma unroll
      for (int j = 0; j < 4; ++j) {
        const float4 w0 = wp[2 * j];
        const float4 w1 = wp[2 * j + 1];
        u[c][j] = w0.x * xa.x + w0.y * xa.y + w0.z * xa.z + w0.w * xa.w
                + w1.x * xb.x + w1.y * xb.y + w1.z * xb.z + w1.w * xb.w;
      }
    }

    if constexpr (UNIFORM) {
      #pragma unroll
      for (int c = 0; c < C_N; ++c)
        #pragma unroll
        for (int j = 0; j < 4; ++j) sacc[c][j] += u[c][j];
    } else {
      float bij[C_N];
      #pragma unroll
      for (int c = 0; c < C_N; ++c) {
        float a = u[c][0] * vf[c][0] + u[c][1] * vf[c][1]
                + u[c][2] * vf[c][2] + u[c][3] * vf[c][3];
        a += __shfl_xor(a, 1);
        a += __shfl_xor(a, 2);
        bij[c] = a;
      }
      float m = bij[0];
      #pragma unroll
      for (int c = 1; c < C_N; ++c) m = fmaxf(m, bij[c]);
      float e[C_N];
      float den = 0.0f;
      #pragma unroll
      for (int c = 0; c < C_N; ++c) { e[c] = __expf(bij[c] - m); den += e[c]; }
      const float inv = __builtin_amdgcn_rcpf(den);
      #pragma unroll
      for (int c = 0; c < C_N; ++c) {
        const float cc = e[c] * inv;
        #pragma unroll
        for (int j = 0; j < 4; ++j) sacc[c][j] += cc * u[c][j];
      }
    }
    xa = nxa; xb = nxb;
  }

  const float scale = UNIFORM ? 0.1f : 1.0f;
  float* p = part + (size_t)rtile * SEG + ((size_t)b * C_N) * O_N + obase;
  #pragma unroll
  for (int c = 0; c < C_N; ++c) {
    float4 v;
    v.x = sacc[c][0] * scale; v.y = sacc[c][1] * scale;
    v.z = sacc[c][2] * scale; v.w = sacc[c][3] * scale;
    *reinterpret_cast<float4*>(p + c * O_N) = v;
  }
}

// reduce over rtiles + squash over O=16 per (b,c). grid = SEG/64 blocks.
// 4 waves each sum a strided rt-subset of 64 outputs; LDS combine; wave0 squashes.
// MODE 0: vsum = v ; MODE 1: vsum += v ; MODE 2: out = v
template<int MODE>
__global__ __launch_bounds__(256) void reduce_squash(
    const float* __restrict__ part, int nrt,
    float* __restrict__ vsum, float* __restrict__ out)
{
  __shared__ float lds[4][64];
  const int tid = threadIdx.x;
  const int l   = tid & 63;
  const int q   = tid >> 6;
  const int j   = blockIdx.x * 64 + l;
  const float* p = part + j;
  float sv = 0.0f;
  #pragma unroll 4
  for (int rt = q; rt < nrt; rt += 4) sv += p[(size_t)rt * SEG];
  lds[q][l] = sv;
  __syncthreads();
  if (q == 0) {
    sv = lds[0][l] + lds[1][l] + lds[2][l] + lds[3][l];
    float sq = sv * sv;
    sq += __shfl_xor(sq, 1);
    sq += __shfl_xor(sq, 2);
    sq += __shfl_xor(sq, 4);
    sq += __shfl_xor(sq, 8);
    const float scale = sq / (1.0f + sq) * rsqrtf(sq + 1e-8f);
    const float v = scale * sv;
    if constexpr (MODE == 0)      vsum[j] = v;
    else if constexpr (MODE == 1) vsum[j] += v;
    else                          out[j] = v;
  }
}

extern "C" void kernel_launch(void* const* d_in, const int* in_sizes, int n_in,
                              void* d_out, int out_size, void* d_ws, size_t ws_size,
                              hipStream_t stream) {
  (void)in_sizes; (void)n_in; (void)out_size;
  const float* x = (const float*)d_in[0];
  const float* W = (const float*)d_in[1];
  float* out  = (float*)d_out;   // doubles as vsum; fully rewritten with v2
  float* part = (float*)d_ws;

  // pick largest RT (integral RCH) whose partials (+ x_t if possible) fit ws
  const int rts[] = {192, 128, 96, 64, 48, 32, 24, 16, 12, 8, 6, 4, 3, 2};
  const size_t xtb = XT_ELEMS * sizeof(float);
  int RT = 0; bool use_xt = false;
  for (int rt : rts)
    if ((size_t)rt * SEG * sizeof(float) + xtb <= ws_size) { RT = rt; use_xt = true; break; }
  if (!RT)
    for (int rt : rts)
      if ((size_t)rt * SEG * sizeof(float) <= ws_size) { RT = rt; break; }
  if (!RT) RT = 1;
  const int RCH = R_TOT / RT;
  float* xt = part + (size_t)RT * SEG;
  const float* xin = use_xt ? xt : x;

  const dim3 blk(256), accGrid(RT, 8), sqGrid(SEG / 64);

  if (use_xt)
    hipLaunchKernelGGL(transpose_x, dim3((B_TOT * R_TOT) / 256), blk, 0, stream, x, xt);

  #define ACC(UNI) do { \
    if (use_xt) hipLaunchKernelGGL((acc_kernel<UNI, true>),  accGrid, blk, 0, stream, xin, W, out, part, RCH); \
    else        hipLaunchKernelGGL((acc_kernel<UNI, false>), accGrid, blk, 0, stream, xin, W, out, part, RCH); \
  } while (0)

  // iter 0: uniform coefficients (softmax of zeros)
  ACC(true);
  hipLaunchKernelGGL((reduce_squash<0>), sqGrid, blk, 0, stream, part, RT, out, out);  // vsum = v0
  // iter 1
  ACC(false);
  hipLaunchKernelGGL((reduce_squash<1>), sqGrid, blk, 0, stream, part, RT, out, out);  // vsum = v0+v1
  // iter 2
  ACC(false);
  hipLaunchKernelGGL((reduce_squash<2>), sqGrid, blk, 0, stream, part, RT, out, out);  // out = v2
  #undef ACC
}

// Round 4
// 197.051 us; speedup vs baseline: 7.0966x; 7.0966x over previous
//
#include <hip/hip_runtime.h>
#include <math.h>

// Capsule dynamic routing, fused-recompute formulation. fp32.
// B=512, R=1152, C=10, O=16, I=8.
//   iter0: c_ij = 1/10 uniform  -> s0 = 0.1 * sum_r u_hat
//   iter2: b2 = u.(v0+v1)       -> only a running vsum kept
// R3 post-mortem: launch_bounds(256,3) + unroll-2 spilled acc arrays to
// scratch (1.65 GB/dispatch!). Reverted.
// R4: W staged in LDS (double-buffered, XOR-swizzled granules so the 4
// ol-groups hit disjoint bank quads; reads are 16-lane broadcasts with
// all offsets folded into ds_read immediates). x prefetched one r ahead.
// Replaces 80 per-thread global float4 loads/r with LDS broadcasts.

#define R_TOT 1152
#define C_N 10
#define O_N 16
#define I_N 8
#define B_TOT 512
#define SEG (B_TOT * C_N * O_N)                 // 81920 floats per partial slice
#define XT_ELEMS ((size_t)B_TOT * R_TOT * I_N)  // 18.9 MB
#define WSLAB (C_N * O_N * I_N)                 // 1280 floats per r
#define GRAN (WSLAB / 4)                        // 320 float4 granules per r

// granule swizzle: XOR bits[2:1] with bits[4:3] (involution, stays in-slab).
// For compute reads G = c*32 + ol*8 + j*2 + h this gives banks
// (j^ol)*2*4 .. distinct across ol -> conflict-free broadcast reads.
__device__ __forceinline__ int swz(int g) { return g ^ (((g >> 3) & 3) << 1); }

// x[b][r][i] -> x_t[r][b][i]
__global__ __launch_bounds__(256) void transpose_x(
    const float* __restrict__ x, float* __restrict__ xt)
{
  const int t = blockIdx.x * 256 + threadIdx.x;   // t = b*R_TOT + r
  const int b = t / R_TOT;
  const int r = t - b * R_TOT;
  const float4* src = reinterpret_cast<const float4*>(x) + (size_t)t * 2;
  float4* dst = reinterpret_cast<float4*>(xt) + ((size_t)r * B_TOT + b) * 2;
  dst[0] = src[0];
  dst[1] = src[1];
}

// lane map: ol = lane&3 owns o in [ol*4,ol*4+4); bl = lane>>2 (16 b / wave)
// grid: (RT, 8) -> blockIdx.x = rtile, blockIdx.y = btile (64 b / block)
template<bool UNIFORM, bool XT>
__global__ __launch_bounds__(256) void acc_kernel(
    const float* __restrict__ x, const float* __restrict__ W,
    const float* __restrict__ vsum, float* __restrict__ part, int RCH)
{
  __shared__ float4 wbuf[2][GRAN];

  const int tid   = threadIdx.x;
  const int wave  = tid >> 6;
  const int lane  = tid & 63;
  const int ol    = lane & 3;
  const int bl    = lane >> 2;
  const int obase = ol * 4;
  const int rtile = blockIdx.x;
  const int btile = blockIdx.y;
  const int b     = btile * 64 + wave * 16 + bl;
  const int r0    = rtile * RCH;

  auto stage = [&](int r, int buf) {
    const float4* wr = reinterpret_cast<const float4*>(W) + (size_t)r * GRAN;
    wbuf[buf][swz(tid)] = wr[tid];
    if (tid < GRAN - 256) wbuf[buf][swz(tid + 256)] = wr[tid + 256];
  };

  auto xaddr = [&](int r) -> const float4* {
    if constexpr (XT)
      return reinterpret_cast<const float4*>(x) + ((size_t)r * B_TOT + b) * 2;
    else
      return reinterpret_cast<const float4*>(x) + ((size_t)b * R_TOT + r) * 2;
  };

  float vf[C_N][4];
  if constexpr (!UNIFORM) {
    #pragma unroll
    for (int c = 0; c < C_N; ++c) {
      const float4 t = *reinterpret_cast<const float4*>(&vsum[(b * C_N + c) * O_N + obase]);
      vf[c][0] = t.x; vf[c][1] = t.y; vf[c][2] = t.z; vf[c][3] = t.w;
    }
  }

  float sacc[C_N][4];
  #pragma unroll
  for (int c = 0; c < C_N; ++c)
    #pragma unroll
    for (int j = 0; j < 4; ++j) sacc[c][j] = 0.0f;

  stage(r0, 0);
  float4 xa = xaddr(r0)[0];
  float4 xb = xaddr(r0)[1];
  __syncthreads();

  int cur = 0;
  #pragma unroll 1
  for (int rr = 0; rr < RCH; ++rr) {
    // stage next W slab into the other buffer (overlaps this iter's compute)
    if (rr + 1 < RCH) stage(r0 + rr + 1, cur ^ 1);
    // prefetch next x (clamped duplicate on last iter)
    const int rn = (rr + 1 < RCH) ? (r0 + rr + 1) : (r0 + rr);
    const float4 nxa = xaddr(rn)[0];
    const float4 nxb = xaddr(rn)[1];

    // swizzled per-j base pointers; ds offsets fold to immediates (c*32 granules)
    const float4* p0 = &wbuf[cur][ol * 8 + ((0 ^ ol) << 1)];
    const float4* p1 = &wbuf[cur][ol * 8 + ((1 ^ ol) << 1)];
    const float4* p2 = &wbuf[cur][ol * 8 + ((2 ^ ol) << 1)];
    const float4* p3 = &wbuf[cur][ol * 8 + ((3 ^ ol) << 1)];

    float u[C_N][4];
    #pragma unroll
    for (int c = 0; c < C_N; ++c) {
      const float4 a0 = p0[c * 32], b0 = p0[c * 32 + 1];
      u[c][0] = a0.x * xa.x + a0.y * xa.y + a0.z * xa.z + a0.w * xa.w
              + b0.x * xb.x + b0.y * xb.y + b0.z * xb.z + b0.w * xb.w;
      const float4 a1 = p1[c * 32], b1 = p1[c * 32 + 1];
      u[c][1] = a1.x * xa.x + a1.y * xa.y + a1.z * xa.z + a1.w * xa.w
              + b1.x * xb.x + b1.y * xb.y + b1.z * xb.z + b1.w * xb.w;
      const float4 a2 = p2[c * 32], b2 = p2[c * 32 + 1];
      u[c][2] = a2.x * xa.x + a2.y * xa.y + a2.z * xa.z + a2.w * xa.w
              + b2.x * xb.x + b2.y * xb.y + b2.z * xb.z + b2.w * xb.w;
      const float4 a3 = p3[c * 32], b3 = p3[c * 32 + 1];
      u[c][3] = a3.x * xa.x + a3.y * xa.y + a3.z * xa.z + a3.w * xa.w
              + b3.x * xb.x + b3.y * xb.y + b3.z * xb.z + b3.w * xb.w;
    }

    if constexpr (UNIFORM) {
      #pragma unroll
      for (int c = 0; c < C_N; ++c)
        #pragma unroll
        for (int j = 0; j < 4; ++j) sacc[c][j] += u[c][j];
    } else {
      float bij[C_N];
      #pragma unroll
      for (int c = 0; c < C_N; ++c) {
        float a = u[c][0] * vf[c][0] + u[c][1] * vf[c][1]
                + u[c][2] * vf[c][2] + u[c][3] * vf[c][3];
        a += __shfl_xor(a, 1);
        a += __shfl_xor(a, 2);
        bij[c] = a;
      }
      float m = bij[0];
      #pragma unroll
      for (int c = 1; c < C_N; ++c) m = fmaxf(m, bij[c]);
      float e[C_N];
      float den = 0.0f;
      #pragma unroll
      for (int c = 0; c < C_N; ++c) { e[c] = __expf(bij[c] - m); den += e[c]; }
      const float inv = __builtin_amdgcn_rcpf(den);
      #pragma unroll
      for (int c = 0; c < C_N; ++c) {
        const float cc = e[c] * inv;
        #pragma unroll
        for (int j = 0; j < 4; ++j) sacc[c][j] += cc * u[c][j];
      }
    }

    __syncthreads();
    cur ^= 1;
    xa = nxa; xb = nxb;
  }

  const float scale = UNIFORM ? 0.1f : 1.0f;
  float* p = part + (size_t)rtile * SEG + ((size_t)b * C_N) * O_N + obase;
  #pragma unroll
  for (int c = 0; c < C_N; ++c) {
    float4 v;
    v.x = sacc[c][0] * scale; v.y = sacc[c][1] * scale;
    v.z = sacc[c][2] * scale; v.w = sacc[c][3] * scale;
    *reinterpret_cast<float4*>(p + c * O_N) = v;
  }
}

// reduce over rtiles + squash over O=16 per (b,c). grid = SEG/64 blocks.
// MODE 0: vsum = v ; MODE 1: vsum += v ; MODE 2: out = v
template<int MODE>
__global__ __launch_bounds__(256) void reduce_squash(
    const float* __restrict__ part, int nrt,
    float* __restrict__ vsum, float* __restrict__ out)
{
  __shared__ float lds[4][64];
  const int tid = threadIdx.x;
  const int l   = tid & 63;
  const int q   = tid >> 6;
  const int j   = blockIdx.x * 64 + l;
  const float* p = part + j;
  float sv = 0.0f;
  #pragma unroll 4
  for (int rt = q; rt < nrt; rt += 4) sv += p[(size_t)rt * SEG];
  lds[q][l] = sv;
  __syncthreads();
  if (q == 0) {
    sv = lds[0][l] + lds[1][l] + lds[2][l] + lds[3][l];
    float sq = sv * sv;
    sq += __shfl_xor(sq, 1);
    sq += __shfl_xor(sq, 2);
    sq += __shfl_xor(sq, 4);
    sq += __shfl_xor(sq, 8);
    const float scale = sq / (1.0f + sq) * rsqrtf(sq + 1e-8f);
    const float v = scale * sv;
    if constexpr (MODE == 0)      vsum[j] = v;
    else if constexpr (MODE == 1) vsum[j] += v;
    else                          out[j] = v;
  }
}

extern "C" void kernel_launch(void* const* d_in, const int* in_sizes, int n_in,
                              void* d_out, int out_size, void* d_ws, size_t ws_size,
                              hipStream_t stream) {
  (void)in_sizes; (void)n_in; (void)out_size;
  const float* x = (const float*)d_in[0];
  const float* W = (const float*)d_in[1];
  float* out  = (float*)d_out;   // doubles as vsum; fully rewritten with v2
  float* part = (float*)d_ws;

  // largest RT (integral RCH) whose partials (+ x_t if possible) fit ws
  const int rts[] = {128, 96, 192, 64, 48, 32, 24, 16, 12, 8, 6, 4, 3, 2};
  const size_t xtb = XT_ELEMS * sizeof(float);
  int RT = 0; bool use_xt = false;
  for (int rt : rts)
    if ((size_t)rt * SEG * sizeof(float) + xtb <= ws_size) { RT = rt; use_xt = true; break; }
  if (!RT)
    for (int rt : rts)
      if ((size_t)rt * SEG * sizeof(float) <= ws_size) { RT = rt; break; }
  if (!RT) RT = 1;
  const int RCH = R_TOT / RT;
  float* xt = part + (size_t)RT * SEG;
  const float* xin = use_xt ? xt : x;

  const dim3 blk(256), accGrid(RT, 8), sqGrid(SEG / 64);

  if (use_xt)
    hipLaunchKernelGGL(transpose_x, dim3((B_TOT * R_TOT) / 256), blk, 0, stream, x, xt);

  #define ACC(UNI) do { \
    if (use_xt) hipLaunchKernelGGL((acc_kernel<UNI, true>),  accGrid, blk, 0, stream, xin, W, out, part, RCH); \
    else        hipLaunchKernelGGL((acc_kernel<UNI, false>), accGrid, blk, 0, stream, xin, W, out, part, RCH); \
  } while (0)

  // iter 0: uniform coefficients (softmax of zeros)
  ACC(true);
  hipLaunchKernelGGL((reduce_squash<0>), sqGrid, blk, 0, stream, part, RT, out, out);  // vsum = v0
  // iter 1
  ACC(false);
  hipLaunchKernelGGL((reduce_squash<1>), sqGrid, blk, 0, stream, part, RT, out, out);  // vsum = v0+v1
  // iter 2
  ACC(false);
  hipLaunchKernelGGL((reduce_squash<2>), sqGrid, blk, 0, stream, part, RT, out, out);  // out = v2
  #undef ACC
}

// Round 5
// 189.091 us; speedup vs baseline: 7.3954x; 1.0421x over previous
//
#include <hip/hip_runtime.h>
#include <math.h>

// Capsule dynamic routing, fused-recompute. fp32.
// B=512, R=1152, C=10, O=16, I=8.
//   iter0: c_ij = 1/10 uniform  -> s0 = 0.1 * sum_r u_hat
//   iter2: b2 = u.(v0+v1)       -> only running vsum kept
// R4 post-mortem: LDS-return-BW bound (80 ds_read_b128/thread/r = 3.0 GB
// per pass at ~42 TB/s = the whole 72 us). Bytes/FMA = 4/B_t.
// R5: B_t=2 (each thread owns 2 b's -> W bytes halve). Lane map:
// oq(2b) x ch(1b) x bl(3b); thread owns 5c x 1 o-quad x 2 b (state 120f).
// Agreement: 4-dot + shfl_xor(1,2); softmax max/den: + shfl_xor(4).
// W granule XOR-swizzle g^=((g>>3)&7): the 8 distinct (ch,oq) addresses
// per ds_read land in 8 distinct bank-quads (conflict-free); offsets fold
// to immediates via 8 base pointers + compile-time double-buffer index.
// x read per-thread from x_t (VMEM pipe idle), prefetched one r ahead.

#define R_TOT 1152
#define C_N 10
#define O_N 16
#define I_N 8
#define B_TOT 512
#define SEG (B_TOT * C_N * O_N)                 // 81920 floats per partial slice
#define XT_ELEMS ((size_t)B_TOT * R_TOT * I_N)  // 18.9 MB
#define WSLAB (C_N * O_N * I_N)                 // 1280 floats per r
#define GRAN (WSLAB / 4)                        // 320 float4 granules per r

// granule swizzle: XOR bits[2:0] with bits[5:3] (within-row permutation).
__device__ __forceinline__ int swz(int g) { return g ^ ((g >> 3) & 7); }

// x[b][r][i] -> x_t[r][b][i]
__global__ __launch_bounds__(256) void transpose_x(
    const float* __restrict__ x, float* __restrict__ xt)
{
  const int t = blockIdx.x * 256 + threadIdx.x;   // t = b*R_TOT + r
  const int b = t / R_TOT;
  const int r = t - b * R_TOT;
  const float4* src = reinterpret_cast<const float4*>(x) + (size_t)t * 2;
  float4* dst = reinterpret_cast<float4*>(xt) + ((size_t)r * B_TOT + b) * 2;
  dst[0] = src[0];
  dst[1] = src[1];
}

// one r-step: u = W.x for this thread's (5c x 4o x 2b), then routing update.
// BUF compile-time -> all ds_read offsets are immediates.
template<int BUF, bool UNIFORM>
__device__ __forceinline__ void body(
    const float4* const (&A)[8],
    const float (&xc)[2][8],
    const float (&vf)[5][2][4],
    float (&sacc)[5][2][4])
{
  float u[5][2][4];
  #pragma unroll
  for (int cc = 0; cc < 5; ++cc) {
    #pragma unroll
    for (int jo = 0; jo < 4; ++jo) {
      // granule = c*32 + oq*8 + ((jo*2+h) ^ xv ^ ((cc&1)<<2)); A[] holds
      // ch*160 + oq*8 + (j^xv); cc-parity re-picks A[j^4] at compile time.
      const float4 w0 = A[(2 * jo)     ^ ((cc & 1) << 2)][cc * 32 + BUF * GRAN];
      const float4 w1 = A[(2 * jo + 1) ^ ((cc & 1) << 2)][cc * 32 + BUF * GRAN];
      #pragma unroll
      for (int k = 0; k < 2; ++k) {
        u[cc][k][jo] =
            w0.x * xc[k][0] + w0.y * xc[k][1] + w0.z * xc[k][2] + w0.w * xc[k][3]
          + w1.x * xc[k][4] + w1.y * xc[k][5] + w1.z * xc[k][6] + w1.w * xc[k][7];
      }
    }
  }

  if constexpr (UNIFORM) {
    #pragma unroll
    for (int cc = 0; cc < 5; ++cc)
      #pragma unroll
      for (int k = 0; k < 2; ++k)
        #pragma unroll
        for (int jo = 0; jo < 4; ++jo)
          sacc[cc][k][jo] += u[cc][k][jo];
  } else {
    // agreement: bij = sum_o u*vsum ; o-sum = in-thread 4 + oq-lane reduce
    float bij[5][2];
    #pragma unroll
    for (int cc = 0; cc < 5; ++cc) {
      #pragma unroll
      for (int k = 0; k < 2; ++k) {
        float a = u[cc][k][0] * vf[cc][k][0] + u[cc][k][1] * vf[cc][k][1]
                + u[cc][k][2] * vf[cc][k][2] + u[cc][k][3] * vf[cc][k][3];
        a += __shfl_xor(a, 1);
        a += __shfl_xor(a, 2);
        bij[cc][k] = a;
      }
    }
    // softmax over all 10 c: local 5 + ch-lane (xor 4) combine
    #pragma unroll
    for (int k = 0; k < 2; ++k) {
      float m = bij[0][k];
      #pragma unroll
      for (int cc = 1; cc < 5; ++cc) m = fmaxf(m, bij[cc][k]);
      m = fmaxf(m, __shfl_xor(m, 4));
      float e[5];
      float den = 0.0f;
      #pragma unroll
      for (int cc = 0; cc < 5; ++cc) { e[cc] = __expf(bij[cc][k] - m); den += e[cc]; }
      den += __shfl_xor(den, 4);
      const float inv = __builtin_amdgcn_rcpf(den);
      #pragma unroll
      for (int cc = 0; cc < 5; ++cc) {
        const float cw = e[cc] * inv;
        #pragma unroll
        for (int jo = 0; jo < 4; ++jo)
          sacc[cc][k][jo] += cw * u[cc][k][jo];
      }
    }
  }
}

// lane map: oq = lane&3 (o-quad), ch = (lane>>2)&1 (c-half), bl = lane>>3.
// thread owns b0 = btile*64 + wave*16 + bl*2 (+k), c = ch*5+cc, o = oq*4+jo.
// grid: (RT, 8); RCH even (r-loop unrolled x2 for compile-time buffer).
template<bool UNIFORM>
__global__ __launch_bounds__(256) void acc_kernel(
    const float* __restrict__ xt, const float* __restrict__ W,
    const float* __restrict__ vsum, float* __restrict__ part, int RCH)
{
  __shared__ float4 wbuf[2 * GRAN];   // 10 KB double-buffered W slab

  const int tid   = threadIdx.x;
  const int wave  = tid >> 6;
  const int lane  = tid & 63;
  const int oq    = lane & 3;
  const int ch    = (lane >> 2) & 1;
  const int bl    = lane >> 3;
  const int rtile = blockIdx.x;
  const int btile = blockIdx.y;
  const int b0    = btile * 64 + wave * 16 + bl * 2;
  const int r0    = rtile * RCH;

  // 8 swizzled LDS base pointers (granules): ch*160 + oq*8 + (j ^ xv)
  const int xv = (ch << 2) | oq;
  const float4* A[8];
  #pragma unroll
  for (int j = 0; j < 8; ++j)
    A[j] = &wbuf[ch * 160 + oq * 8 + (j ^ xv)];

  float vf[5][2][4];
  if constexpr (!UNIFORM) {
    #pragma unroll
    for (int cc = 0; cc < 5; ++cc)
      #pragma unroll
      for (int k = 0; k < 2; ++k) {
        const float4 t = *reinterpret_cast<const float4*>(
            &vsum[((b0 + k) * C_N + ch * 5 + cc) * O_N + oq * 4]);
        vf[cc][k][0] = t.x; vf[cc][k][1] = t.y; vf[cc][k][2] = t.z; vf[cc][k][3] = t.w;
      }
  }

  float sacc[5][2][4];
  #pragma unroll
  for (int cc = 0; cc < 5; ++cc)
    #pragma unroll
    for (int k = 0; k < 2; ++k)
      #pragma unroll
      for (int jo = 0; jo < 4; ++jo) sacc[cc][k][jo] = 0.0f;

  auto stage = [&](int r, int buf) {
    const float4* wr = reinterpret_cast<const float4*>(W) + (size_t)r * GRAN;
    wbuf[buf * GRAN + swz(tid)] = wr[tid];
    if (tid < GRAN - 256) wbuf[buf * GRAN + swz(tid + 256)] = wr[tid + 256];
  };

  auto xload = [&](int r, float (&dst)[2][8]) {
    const float4* xp = reinterpret_cast<const float4*>(xt) + ((size_t)r * B_TOT + b0) * 2;
    #pragma unroll
    for (int k = 0; k < 2; ++k) {
      const float4 a = xp[2 * k], b = xp[2 * k + 1];
      dst[k][0] = a.x; dst[k][1] = a.y; dst[k][2] = a.z; dst[k][3] = a.w;
      dst[k][4] = b.x; dst[k][5] = b.y; dst[k][6] = b.z; dst[k][7] = b.w;
    }
  };

  float xc[2][8], xn[2][8];
  stage(r0, 0);
  xload(r0, xc);
  __syncthreads();

  #pragma unroll 1
  for (int rr = 0; rr < RCH; rr += 2) {
    // --- even r: buffer 0 ---
    stage(r0 + rr + 1, 1);                       // RCH even -> always valid
    xload(r0 + rr + 1, xn);
    body<0, UNIFORM>(A, xc, vf, sacc);
    __syncthreads();
    #pragma unroll
    for (int k = 0; k < 2; ++k)
      #pragma unroll
      for (int i = 0; i < 8; ++i) xc[k][i] = xn[k][i];

    // --- odd r: buffer 1 ---
    if (rr + 2 < RCH) {
      stage(r0 + rr + 2, 0);
      xload(r0 + rr + 2, xn);
    }
    body<1, UNIFORM>(A, xc, vf, sacc);
    __syncthreads();
    #pragma unroll
    for (int k = 0; k < 2; ++k)
      #pragma unroll
      for (int i = 0; i < 8; ++i) xc[k][i] = xn[k][i];
  }

  const float scale = UNIFORM ? 0.1f : 1.0f;
  float* pb = part + (size_t)rtile * SEG;
  #pragma unroll
  for (int cc = 0; cc < 5; ++cc)
    #pragma unroll
    for (int k = 0; k < 2; ++k) {
      float4 v;
      v.x = sacc[cc][k][0] * scale; v.y = sacc[cc][k][1] * scale;
      v.z = sacc[cc][k][2] * scale; v.w = sacc[cc][k][3] * scale;
      *reinterpret_cast<float4*>(
          &pb[((b0 + k) * C_N + ch * 5 + cc) * O_N + oq * 4]) = v;
    }
}

// reduce over rtiles + squash over O=16 per (b,c). grid = SEG/64 blocks.
// MODE 0: vsum = v ; MODE 1: vsum += v ; MODE 2: out = v
template<int MODE>
__global__ __launch_bounds__(256) void reduce_squash(
    const float* __restrict__ part, int nrt,
    float* __restrict__ vsum, float* __restrict__ out)
{
  __shared__ float lds[4][64];
  const int tid = threadIdx.x;
  const int l   = tid & 63;
  const int q   = tid >> 6;
  const int j   = blockIdx.x * 64 + l;
  const float* p = part + j;
  float sv = 0.0f;
  #pragma unroll 4
  for (int rt = q; rt < nrt; rt += 4) sv += p[(size_t)rt * SEG];
  lds[q][l] = sv;
  __syncthreads();
  if (q == 0) {
    sv = lds[0][l] + lds[1][l] + lds[2][l] + lds[3][l];
    float sq = sv * sv;
    sq += __shfl_xor(sq, 1);
    sq += __shfl_xor(sq, 2);
    sq += __shfl_xor(sq, 4);
    sq += __shfl_xor(sq, 8);
    const float scale = sq / (1.0f + sq) * rsqrtf(sq + 1e-8f);
    const float v = scale * sv;
    if constexpr (MODE == 0)      vsum[j] = v;
    else if constexpr (MODE == 1) vsum[j] += v;
    else                          out[j] = v;
  }
}

extern "C" void kernel_launch(void* const* d_in, const int* in_sizes, int n_in,
                              void* d_out, int out_size, void* d_ws, size_t ws_size,
                              hipStream_t stream) {
  (void)in_sizes; (void)n_in; (void)out_size;
  const float* x = (const float*)d_in[0];
  const float* W = (const float*)d_in[1];
  float* out  = (float*)d_out;   // doubles as vsum; fully rewritten with v2
  float* part = (float*)d_ws;

  // largest RT with even RCH whose partials + x_t fit ws
  const int rts[] = {96, 64, 48, 32, 24, 16, 12, 8, 6, 4, 2};
  const size_t xtb = XT_ELEMS * sizeof(float);
  int RT = 2;
  for (int rt : rts)
    if ((size_t)rt * SEG * sizeof(float) + xtb <= ws_size) { RT = rt; break; }
  const int RCH = R_TOT / RT;
  float* xt = part + (size_t)RT * SEG;

  const dim3 blk(256), accGrid(RT, 8), sqGrid(SEG / 64);

  hipLaunchKernelGGL(transpose_x, dim3((B_TOT * R_TOT) / 256), blk, 0, stream, x, xt);

  // iter 0: uniform coefficients (softmax of zeros)
  hipLaunchKernelGGL((acc_kernel<true>),  accGrid, blk, 0, stream, xt, W, out, part, RCH);
  hipLaunchKernelGGL((reduce_squash<0>),  sqGrid,  blk, 0, stream, part, RT, out, out);  // vsum = v0
  // iter 1
  hipLaunchKernelGGL((acc_kernel<false>), accGrid, blk, 0, stream, xt, W, out, part, RCH);
  hipLaunchKernelGGL((reduce_squash<1>),  sqGrid,  blk, 0, stream, part, RT, out, out);  // vsum = v0+v1
  // iter 2
  hipLaunchKernelGGL((acc_kernel<false>), accGrid, blk, 0, stream, xt, W, out, part, RCH);
  hipLaunchKernelGGL((reduce_squash<2>),  sqGrid,  blk, 0, stream, part, RT, out, out);  // out = v2
}

// Round 6
// 183.430 us; speedup vs baseline: 7.6236x; 1.0309x over previous
//
#include <hip/hip_runtime.h>
#include <math.h>

// Capsule dynamic routing, fused-recompute. fp32.
// B=512, R=1152, C=10, O=16, I=8.
//   iter0: c_ij = 1/10 uniform  -> s0 = 0.1 * sum_r u_hat
//   iter2: b2 = u.(v0+v1)       -> only running vsum kept
// R5 post-mortem: pass is ~2.3x above the 29us LDS-instr floor; the gap
// is the per-r __syncthreads + staging dependency chain (global->vmcnt->
// ds_write->barrier exposed every iter at 3 blocks/CU).
// R6: stage the block's WHOLE r-chunk (RCH x 5KB <= 60KB) into LDS once,
// ONE barrier, then a barrier-free r-loop (pure ds_read+FMA+shuffle).
// Same conflict-free XOR-swizzled W layout as R5 (0 conflicts measured).
// Grid flipped to (btile, rtile) so consecutive blocks share W slabs in L2.

#define R_TOT 1152
#define C_N 10
#define O_N 16
#define I_N 8
#define B_TOT 512
#define SEG (B_TOT * C_N * O_N)                 // 81920 floats per partial slice
#define XT_ELEMS ((size_t)B_TOT * R_TOT * I_N)  // 18.9 MB
#define WSLAB (C_N * O_N * I_N)                 // 1280 floats per r
#define GRAN (WSLAB / 4)                        // 320 float4 granules per r

// granule swizzle within a slab: XOR bits[2:0] with bits[5:3] (involution).
__device__ __forceinline__ int swz(int g) { return g ^ ((g >> 3) & 7); }

// x[b][r][i] -> x_t[r][b][i]
__global__ __launch_bounds__(256) void transpose_x(
    const float* __restrict__ x, float* __restrict__ xt)
{
  const int t = blockIdx.x * 256 + threadIdx.x;   // t = b*R_TOT + r
  const int b = t / R_TOT;
  const int r = t - b * R_TOT;
  const float4* src = reinterpret_cast<const float4*>(x) + (size_t)t * 2;
  float4* dst = reinterpret_cast<float4*>(xt) + ((size_t)r * B_TOT + b) * 2;
  dst[0] = src[0];
  dst[1] = src[1];
}

// one r-step: u = W.x for this thread's (5c x 4o x 2b), then routing update.
template<bool UNIFORM>
__device__ __forceinline__ void body(
    const float4* const (&A)[8], int slab,     // slab = rr*GRAN (runtime)
    const float (&xc)[2][8],
    const float (&vf)[5][2][4],
    float (&sacc)[5][2][4])
{
  float u[5][2][4];
  #pragma unroll
  for (int cc = 0; cc < 5; ++cc) {
    #pragma unroll
    for (int jo = 0; jo < 4; ++jo) {
      const float4 w0 = A[(2 * jo)     ^ ((cc & 1) << 2)][slab + cc * 32];
      const float4 w1 = A[(2 * jo + 1) ^ ((cc & 1) << 2)][slab + cc * 32];
      #pragma unroll
      for (int k = 0; k < 2; ++k) {
        u[cc][k][jo] =
            w0.x * xc[k][0] + w0.y * xc[k][1] + w0.z * xc[k][2] + w0.w * xc[k][3]
          + w1.x * xc[k][4] + w1.y * xc[k][5] + w1.z * xc[k][6] + w1.w * xc[k][7];
      }
    }
  }

  if constexpr (UNIFORM) {
    #pragma unroll
    for (int cc = 0; cc < 5; ++cc)
      #pragma unroll
      for (int k = 0; k < 2; ++k)
        #pragma unroll
        for (int jo = 0; jo < 4; ++jo)
          sacc[cc][k][jo] += u[cc][k][jo];
  } else {
    float bij[5][2];
    #pragma unroll
    for (int cc = 0; cc < 5; ++cc) {
      #pragma unroll
      for (int k = 0; k < 2; ++k) {
        float a = u[cc][k][0] * vf[cc][k][0] + u[cc][k][1] * vf[cc][k][1]
                + u[cc][k][2] * vf[cc][k][2] + u[cc][k][3] * vf[cc][k][3];
        a += __shfl_xor(a, 1);
        a += __shfl_xor(a, 2);
        bij[cc][k] = a;
      }
    }
    #pragma unroll
    for (int k = 0; k < 2; ++k) {
      float m = bij[0][k];
      #pragma unroll
      for (int cc = 1; cc < 5; ++cc) m = fmaxf(m, bij[cc][k]);
      m = fmaxf(m, __shfl_xor(m, 4));
      float e[5];
      float den = 0.0f;
      #pragma unroll
      for (int cc = 0; cc < 5; ++cc) { e[cc] = __expf(bij[cc][k] - m); den += e[cc]; }
      den += __shfl_xor(den, 4);
      const float inv = __builtin_amdgcn_rcpf(den);
      #pragma unroll
      for (int cc = 0; cc < 5; ++cc) {
        const float cw = e[cc] * inv;
        #pragma unroll
        for (int jo = 0; jo < 4; ++jo)
          sacc[cc][k][jo] += cw * u[cc][k][jo];
      }
    }
  }
}

// lane map: oq = lane&3, ch = (lane>>2)&1, bl = lane>>3; thread owns
// b0 = btile*64 + wave*16 + bl*2 (+k), c = ch*5+cc, o = oq*4+jo.
// grid: (8, RT) -> blockIdx.x = btile, blockIdx.y = rtile.
template<bool UNIFORM>
__global__ __launch_bounds__(256) void acc_kernel(
    const float* __restrict__ xt, const float* __restrict__ W,
    const float* __restrict__ vsum, float* __restrict__ part, int RCH)
{
  extern __shared__ float4 wbuf[];   // RCH * 5KB, whole r-chunk resident

  const int tid   = threadIdx.x;
  const int wave  = tid >> 6;
  const int lane  = tid & 63;
  const int oq    = lane & 3;
  const int ch    = (lane >> 2) & 1;
  const int bl    = lane >> 3;
  const int btile = blockIdx.x;
  const int rtile = blockIdx.y;
  const int b0    = btile * 64 + wave * 16 + bl * 2;
  const int r0    = rtile * RCH;

  // stage ALL slabs, one barrier, no barriers afterwards
  #pragma unroll 1
  for (int rr = 0; rr < RCH; ++rr) {
    const float4* wr = reinterpret_cast<const float4*>(W) + (size_t)(r0 + rr) * GRAN;
    wbuf[rr * GRAN + swz(tid)] = wr[tid];
    if (tid < GRAN - 256) wbuf[rr * GRAN + swz(tid + 256)] = wr[tid + 256];
  }

  // 8 swizzled LDS base pointers (granule units): ch*160 + oq*8 + (j ^ xv)
  const int xv = (ch << 2) | oq;
  const float4* A[8];
  #pragma unroll
  for (int j = 0; j < 8; ++j)
    A[j] = &wbuf[ch * 160 + oq * 8 + (j ^ xv)];

  float vf[5][2][4];
  if constexpr (!UNIFORM) {
    #pragma unroll
    for (int cc = 0; cc < 5; ++cc)
      #pragma unroll
      for (int k = 0; k < 2; ++k) {
        const float4 t = *reinterpret_cast<const float4*>(
            &vsum[((b0 + k) * C_N + ch * 5 + cc) * O_N + oq * 4]);
        vf[cc][k][0] = t.x; vf[cc][k][1] = t.y; vf[cc][k][2] = t.z; vf[cc][k][3] = t.w;
      }
  }

  float sacc[5][2][4];
  #pragma unroll
  for (int cc = 0; cc < 5; ++cc)
    #pragma unroll
    for (int k = 0; k < 2; ++k)
      #pragma unroll
      for (int jo = 0; jo < 4; ++jo) sacc[cc][k][jo] = 0.0f;

  auto xload = [&](int r, float (&dst)[2][8]) {
    const float4* xp = reinterpret_cast<const float4*>(xt) + ((size_t)r * B_TOT + b0) * 2;
    #pragma unroll
    for (int k = 0; k < 2; ++k) {
      const float4 a = xp[2 * k], b = xp[2 * k + 1];
      dst[k][0] = a.x; dst[k][1] = a.y; dst[k][2] = a.z; dst[k][3] = a.w;
      dst[k][4] = b.x; dst[k][5] = b.y; dst[k][6] = b.z; dst[k][7] = b.w;
    }
  };

  float xc[2][8], xn[2][8];
  xload(r0, xc);
  __syncthreads();   // staging complete; last barrier in the kernel

  #pragma unroll 1
  for (int rr = 0; rr < RCH; ++rr) {
    const int rn = (rr + 1 < RCH) ? (r0 + rr + 1) : (r0 + rr);
    xload(rn, xn);                       // prefetch next x under this iter
    body<UNIFORM>(A, rr * GRAN, xc, vf, sacc);
    #pragma unroll
    for (int k = 0; k < 2; ++k)
      #pragma unroll
      for (int i = 0; i < 8; ++i) xc[k][i] = xn[k][i];
  }

  const float scale = UNIFORM ? 0.1f : 1.0f;
  float* pb = part + (size_t)rtile * SEG;
  #pragma unroll
  for (int cc = 0; cc < 5; ++cc)
    #pragma unroll
    for (int k = 0; k < 2; ++k) {
      float4 v;
      v.x = sacc[cc][k][0] * scale; v.y = sacc[cc][k][1] * scale;
      v.z = sacc[cc][k][2] * scale; v.w = sacc[cc][k][3] * scale;
      *reinterpret_cast<float4*>(
          &pb[((b0 + k) * C_N + ch * 5 + cc) * O_N + oq * 4]) = v;
    }
}

// reduce over rtiles + squash over O=16 per (b,c). grid = SEG/64 blocks.
// MODE 0: vsum = v ; MODE 1: vsum += v ; MODE 2: out = v
template<int MODE>
__global__ __launch_bounds__(256) void reduce_squash(
    const float* __restrict__ part, int nrt,
    float* __restrict__ vsum, float* __restrict__ out)
{
  __shared__ float lds[4][64];
  const int tid = threadIdx.x;
  const int l   = tid & 63;
  const int q   = tid >> 6;
  const int j   = blockIdx.x * 64 + l;
  const float* p = part + j;
  float sv = 0.0f;
  #pragma unroll 4
  for (int rt = q; rt < nrt; rt += 4) sv += p[(size_t)rt * SEG];
  lds[q][l] = sv;
  __syncthreads();
  if (q == 0) {
    sv = lds[0][l] + lds[1][l] + lds[2][l] + lds[3][l];
    float sq = sv * sv;
    sq += __shfl_xor(sq, 1);
    sq += __shfl_xor(sq, 2);
    sq += __shfl_xor(sq, 4);
    sq += __shfl_xor(sq, 8);
    const float scale = sq / (1.0f + sq) * rsqrtf(sq + 1e-8f);
    const float v = scale * sv;
    if constexpr (MODE == 0)      vsum[j] = v;
    else if constexpr (MODE == 1) vsum[j] += v;
    else                          out[j] = v;
  }
}

extern "C" void kernel_launch(void* const* d_in, const int* in_sizes, int n_in,
                              void* d_out, int out_size, void* d_ws, size_t ws_size,
                              hipStream_t stream) {
  (void)in_sizes; (void)n_in; (void)out_size;
  const float* x = (const float*)d_in[0];
  const float* W = (const float*)d_in[1];
  float* out  = (float*)d_out;   // doubles as vsum; fully rewritten with v2
  float* part = (float*)d_ws;

  // RT candidates: integral RCH, RCH*5KB <= 60KB LDS, partials+x_t fit ws.
  const int rts[] = {144, 128, 96};   // RCH = 8, 9, 12
  const size_t xtb = XT_ELEMS * sizeof(float);
  int RT = 96;
  for (int rt : rts)
    if ((size_t)rt * SEG * sizeof(float) + xtb <= ws_size) { RT = rt; break; }
  const int RCH = R_TOT / RT;
  const size_t ldsB = (size_t)RCH * GRAN * sizeof(float4);
  float* xt = part + (size_t)RT * SEG;

  const dim3 blk(256), accGrid(8, RT), sqGrid(SEG / 64);

  hipLaunchKernelGGL(transpose_x, dim3((B_TOT * R_TOT) / 256), blk, 0, stream, x, xt);

  // iter 0: uniform coefficients (softmax of zeros)
  hipLaunchKernelGGL((acc_kernel<true>),  accGrid, blk, ldsB, stream, xt, W, out, part, RCH);
  hipLaunchKernelGGL((reduce_squash<0>),  sqGrid,  blk, 0,    stream, part, RT, out, out);  // vsum = v0
  // iter 1
  hipLaunchKernelGGL((acc_kernel<false>), accGrid, blk, ldsB, stream, xt, W, out, part, RCH);
  hipLaunchKernelGGL((reduce_squash<1>),  sqGrid,  blk, 0,    stream, part, RT, out, out);  // vsum = v0+v1
  // iter 2
  hipLaunchKernelGGL((acc_kernel<false>), accGrid, blk, ldsB, stream, xt, W, out, part, RCH);
  hipLaunchKernelGGL((reduce_squash<2>),  sqGrid,  blk, 0,    stream, part, RT, out, out);  // out = v2
}

// Round 7
// 161.378 us; speedup vs baseline: 8.6654x; 1.1367x over previous
//
#include <hip/hip_runtime.h>
#include <math.h>

// Capsule dynamic routing, fused-recompute. fp32.
// B=512, R=1152, C=10, O=16, I=8.
//   iter0: c_ij = 1/10 uniform  -> s0 = 0.1 * sum_r u_hat
//   iter2: b2 = u.(v0+v1)       -> only running vsum kept
// R6 post-mortem: LDS-pipe 44% + VALU 43% ~ serialized (sum ~= wall):
// 2-block/CU tail (768 blocks) + no cross-iter ILP (unroll 1, VGPR 108
// of 256 free). R7: exact-fit grid 512 = 2/CU (no tail); 18 r's per
// block as 3 double-buffered chunks of 6 (2x30KB LDS, 1 barrier/chunk,
// staging hidden under compute); unroll 2 + launch_bounds(256,2) for
// ILP; XCD-chunked block swizzle (each XCD owns its rtile range -> W
// fetched into one L2). Same conflict-free XOR-swizzled W layout.

#define R_TOT 1152
#define C_N 10
#define O_N 16
#define I_N 8
#define B_TOT 512
#define SEG (B_TOT * C_N * O_N)                 // 81920 floats per partial slice
#define XT_ELEMS ((size_t)B_TOT * R_TOT * I_N)  // 18.9 MB
#define WSLAB (C_N * O_N * I_N)                 // 1280 floats per r
#define GRAN (WSLAB / 4)                        // 320 float4 granules per r
#define CHUNK 6                                 // r's per staged chunk
#define CG (CHUNK * GRAN)                       // 1920 granules per chunk

// granule swizzle within a slab: XOR bits[2:0] with bits[5:3] (involution).
__device__ __forceinline__ int swz(int g) { return g ^ ((g >> 3) & 7); }

// x[b][r][i] -> x_t[r][b][i]
__global__ __launch_bounds__(256) void transpose_x(
    const float* __restrict__ x, float* __restrict__ xt)
{
  const int t = blockIdx.x * 256 + threadIdx.x;   // t = b*R_TOT + r
  const int b = t / R_TOT;
  const int r = t - b * R_TOT;
  const float4* src = reinterpret_cast<const float4*>(x) + (size_t)t * 2;
  float4* dst = reinterpret_cast<float4*>(xt) + ((size_t)r * B_TOT + b) * 2;
  dst[0] = src[0];
  dst[1] = src[1];
}

// one r-step: u = W.x for this thread's (5c x 4o x 2b), then routing update.
template<bool UNIFORM>
__device__ __forceinline__ void body(
    const float4* const (&A)[8], int slab,     // slab = granule offset (runtime)
    const float (&xc)[2][8],
    const float (&vf)[5][2][4],
    float (&sacc)[5][2][4])
{
  float u[5][2][4];
  #pragma unroll
  for (int cc = 0; cc < 5; ++cc) {
    #pragma unroll
    for (int jo = 0; jo < 4; ++jo) {
      const float4 w0 = A[(2 * jo)     ^ ((cc & 1) << 2)][slab + cc * 32];
      const float4 w1 = A[(2 * jo + 1) ^ ((cc & 1) << 2)][slab + cc * 32];
      #pragma unroll
      for (int k = 0; k < 2; ++k) {
        u[cc][k][jo] =
            w0.x * xc[k][0] + w0.y * xc[k][1] + w0.z * xc[k][2] + w0.w * xc[k][3]
          + w1.x * xc[k][4] + w1.y * xc[k][5] + w1.z * xc[k][6] + w1.w * xc[k][7];
      }
    }
  }

  if constexpr (UNIFORM) {
    #pragma unroll
    for (int cc = 0; cc < 5; ++cc)
      #pragma unroll
      for (int k = 0; k < 2; ++k)
        #pragma unroll
        for (int jo = 0; jo < 4; ++jo)
          sacc[cc][k][jo] += u[cc][k][jo];
  } else {
    float bij[5][2];
    #pragma unroll
    for (int cc = 0; cc < 5; ++cc) {
      #pragma unroll
      for (int k = 0; k < 2; ++k) {
        float a = u[cc][k][0] * vf[cc][k][0] + u[cc][k][1] * vf[cc][k][1]
                + u[cc][k][2] * vf[cc][k][2] + u[cc][k][3] * vf[cc][k][3];
        a += __shfl_xor(a, 1);
        a += __shfl_xor(a, 2);
        bij[cc][k] = a;
      }
    }
    #pragma unroll
    for (int k = 0; k < 2; ++k) {
      float m = bij[0][k];
      #pragma unroll
      for (int cc = 1; cc < 5; ++cc) m = fmaxf(m, bij[cc][k]);
      m = fmaxf(m, __shfl_xor(m, 4));
      float e[5];
      float den = 0.0f;
      #pragma unroll
      for (int cc = 0; cc < 5; ++cc) { e[cc] = __expf(bij[cc][k] - m); den += e[cc]; }
      den += __shfl_xor(den, 4);
      const float inv = __builtin_amdgcn_rcpf(den);
      #pragma unroll
      for (int cc = 0; cc < 5; ++cc) {
        const float cw = e[cc] * inv;
        #pragma unroll
        for (int jo = 0; jo < 4; ++jo)
          sacc[cc][k][jo] += cw * u[cc][k][jo];
      }
    }
  }
}

// lane map: oq = lane&3, ch = (lane>>2)&1, bl = lane>>3; thread owns
// b0 = btile*64 + wave*16 + bl*2 (+k), c = ch*5+cc, o = oq*4+jo.
// 1D grid of 8*RT blocks; XCD-chunked swizzle maps bid -> (btile, rtile)
// so XCD k owns rtiles [k*RT/8, (k+1)*RT/8) across all btiles.
template<bool UNIFORM>
__global__ __launch_bounds__(256, 2) void acc_kernel(
    const float* __restrict__ xt, const float* __restrict__ W,
    const float* __restrict__ vsum, float* __restrict__ part,
    int RT, int NCH)
{
  __shared__ float4 wbuf[2 * CG];   // 60 KB: two 6-slab chunks

  const int tid   = threadIdx.x;
  const int wave  = tid >> 6;
  const int lane  = tid & 63;
  const int oq    = lane & 3;
  const int ch    = (lane >> 2) & 1;
  const int bl    = lane >> 3;

  const int bid   = blockIdx.x;
  const int rpx   = RT >> 3;              // rtiles per XCD
  const int xcd   = bid & 7;              // dispatch round-robins XCDs
  const int idx   = bid >> 3;
  const int rtile = xcd * rpx + (idx % rpx);
  const int btile = idx / rpx;

  const int b0 = btile * 64 + wave * 16 + bl * 2;
  const int RCHB = NCH * CHUNK;
  const int r0 = rtile * RCHB;

  auto stage = [&](int ci, int bufsel) {
    const float4* wc = reinterpret_cast<const float4*>(W) + (size_t)(r0 + ci * CHUNK) * GRAN;
    #pragma unroll
    for (int s = 0; s < CHUNK; ++s) {
      wbuf[bufsel * CG + s * GRAN + swz(tid)] = wc[s * GRAN + tid];
      if (tid < GRAN - 256)
        wbuf[bufsel * CG + s * GRAN + swz(tid + 256)] = wc[s * GRAN + tid + 256];
    }
  };

  auto xload = [&](int r, float (&dst)[2][8]) {
    const float4* xp = reinterpret_cast<const float4*>(xt) + ((size_t)r * B_TOT + b0) * 2;
    #pragma unroll
    for (int k = 0; k < 2; ++k) {
      const float4 a = xp[2 * k], b = xp[2 * k + 1];
      dst[k][0] = a.x; dst[k][1] = a.y; dst[k][2] = a.z; dst[k][3] = a.w;
      dst[k][4] = b.x; dst[k][5] = b.y; dst[k][6] = b.z; dst[k][7] = b.w;
    }
  };

  // 8 swizzled LDS base pointers (granule units): ch*160 + oq*8 + (j ^ xv)
  const int xv = (ch << 2) | oq;
  const float4* A[8];
  #pragma unroll
  for (int j = 0; j < 8; ++j)
    A[j] = &wbuf[ch * 160 + oq * 8 + (j ^ xv)];

  float vf[5][2][4];
  if constexpr (!UNIFORM) {
    #pragma unroll
    for (int cc = 0; cc < 5; ++cc)
      #pragma unroll
      for (int k = 0; k < 2; ++k) {
        const float4 t = *reinterpret_cast<const float4*>(
            &vsum[((b0 + k) * C_N + ch * 5 + cc) * O_N + oq * 4]);
        vf[cc][k][0] = t.x; vf[cc][k][1] = t.y; vf[cc][k][2] = t.z; vf[cc][k][3] = t.w;
      }
  }

  float sacc[5][2][4];
  #pragma unroll
  for (int cc = 0; cc < 5; ++cc)
    #pragma unroll
    for (int k = 0; k < 2; ++k)
      #pragma unroll
      for (int jo = 0; jo < 4; ++jo) sacc[cc][k][jo] = 0.0f;

  float xc[2][8], xn[2][8];
  stage(0, 0);
  xload(r0, xc);
  __syncthreads();

  #pragma unroll 1
  for (int ci = 0; ci < NCH; ++ci) {
    if (ci + 1 < NCH) stage(ci + 1, (ci + 1) & 1);   // fill other buffer
    const int sb = (ci & 1) * CG;
    #pragma unroll 2
    for (int rr = 0; rr < CHUNK; ++rr) {
      const int rl = ci * CHUNK + rr;
      const int rn = (rl + 1 < RCHB) ? rl + 1 : rl;
      xload(r0 + rn, xn);                 // prefetch next x under compute
      body<UNIFORM>(A, sb + rr * GRAN, xc, vf, sacc);
      #pragma unroll
      for (int k = 0; k < 2; ++k)
        #pragma unroll
        for (int i = 0; i < 8; ++i) xc[k][i] = xn[k][i];
    }
    __syncthreads();   // staged writes visible; old buffer free for reuse
  }

  const float scale = UNIFORM ? 0.1f : 1.0f;
  float* pb = part + (size_t)rtile * SEG;
  #pragma unroll
  for (int cc = 0; cc < 5; ++cc)
    #pragma unroll
    for (int k = 0; k < 2; ++k) {
      float4 v;
      v.x = sacc[cc][k][0] * scale; v.y = sacc[cc][k][1] * scale;
      v.z = sacc[cc][k][2] * scale; v.w = sacc[cc][k][3] * scale;
      *reinterpret_cast<float4*>(
          &pb[((b0 + k) * C_N + ch * 5 + cc) * O_N + oq * 4]) = v;
    }
}

// reduce over rtiles + squash over O=16 per (b,c). grid = SEG/64 blocks.
// MODE 0: vsum = v ; MODE 1: vsum += v ; MODE 2: out = v
template<int MODE>
__global__ __launch_bounds__(256) void reduce_squash(
    const float* __restrict__ part, int nrt,
    float* __restrict__ vsum, float* __restrict__ out)
{
  __shared__ float lds[4][64];
  const int tid = threadIdx.x;
  const int l   = tid & 63;
  const int q   = tid >> 6;
  const int j   = blockIdx.x * 64 + l;
  const float* p = part + j;
  float sv = 0.0f;
  #pragma unroll 4
  for (int rt = q; rt < nrt; rt += 4) sv += p[(size_t)rt * SEG];
  lds[q][l] = sv;
  __syncthreads();
  if (q == 0) {
    sv = lds[0][l] + lds[1][l] + lds[2][l] + lds[3][l];
    float sq = sv * sv;
    sq += __shfl_xor(sq, 1);
    sq += __shfl_xor(sq, 2);
    sq += __shfl_xor(sq, 4);
    sq += __shfl_xor(sq, 8);
    const float scale = sq / (1.0f + sq) * rsqrtf(sq + 1e-8f);
    const float v = scale * sv;
    if constexpr (MODE == 0)      vsum[j] = v;
    else if constexpr (MODE == 1) vsum[j] += v;
    else                          out[j] = v;
  }
}

extern "C" void kernel_launch(void* const* d_in, const int* in_sizes, int n_in,
                              void* d_out, int out_size, void* d_ws, size_t ws_size,
                              hipStream_t stream) {
  (void)in_sizes; (void)n_in; (void)out_size;
  const float* x = (const float*)d_in[0];
  const float* W = (const float*)d_in[1];
  float* out  = (float*)d_out;   // doubles as vsum; fully rewritten with v2
  float* part = (float*)d_ws;

  // RT=64: grid 512 = exactly 2 blocks/CU, RCHB=18 = 3 chunks of 6.
  // Fallback RT=32 (grid 256) if workspace is tight.
  const size_t xtb = XT_ELEMS * sizeof(float);
  int RT = 64;
  if ((size_t)RT * SEG * sizeof(float) + xtb > ws_size) RT = 32;
  const int NCH = (R_TOT / RT) / CHUNK;
  float* xt = part + (size_t)RT * SEG;

  const dim3 blk(256), accGrid(8 * RT), sqGrid(SEG / 64);

  hipLaunchKernelGGL(transpose_x, dim3((B_TOT * R_TOT) / 256), blk, 0, stream, x, xt);

  // iter 0: uniform coefficients (softmax of zeros)
  hipLaunchKernelGGL((acc_kernel<true>),  accGrid, blk, 0, stream, xt, W, out, part, RT, NCH);
  hipLaunchKernelGGL((reduce_squash<0>),  sqGrid,  blk, 0, stream, part, RT, out, out);  // vsum = v0
  // iter 1
  hipLaunchKernelGGL((acc_kernel<false>), accGrid, blk, 0, stream, xt, W, out, part, RT, NCH);
  hipLaunchKernelGGL((reduce_squash<1>),  sqGrid,  blk, 0, stream, part, RT, out, out);  // vsum = v0+v1
  // iter 2
  hipLaunchKernelGGL((acc_kernel<false>), accGrid, blk, 0, stream, xt, W, out, part, RT, NCH);
  hipLaunchKernelGGL((reduce_squash<2>),  sqGrid,  blk, 0, stream, part, RT, out, out);  // out = v2
}